// Round 7
// baseline (310.993 us; speedup 1.0000x reference)
//
#include <hip/hip_runtime.h>

typedef unsigned short u16;
typedef unsigned int u32;

typedef __bf16 bf16x8 __attribute__((ext_vector_type(8)));
typedef float f32x4 __attribute__((ext_vector_type(4)));

__device__ __forceinline__ u16 f2bf(float f) {
  u32 u = __builtin_bit_cast(u32, f);
  u32 r = (u + 0x7fffu + ((u >> 16) & 1u)) >> 16;  // RNE
  return (u16)r;
}
__device__ __forceinline__ float bf2f(u16 v) {
  u32 u = (u32)v << 16;
  return __builtin_bit_cast(float, u);
}

// ---------------- fused f32 -> bf16 convert for all 5 tensors ----------------
__global__ __launch_bounds__(256)
void cvt_all_kernel(const float* __restrict__ x, const float* __restrict__ wq,
                    const float* __restrict__ wk, const float* __restrict__ wv,
                    const float* __restrict__ wo, u16* __restrict__ x_bf,
                    u16* __restrict__ wcat_bf, u16* __restrict__ wo_bf) {
  int t = blockIdx.x * 256 + threadIdx.x;
  const float* src;
  u16* dst;
  if (t < 1048576) {
    src = x; dst = x_bf;
  } else if (t < 1310720) {
    src = wq; dst = wcat_bf; t -= 1048576;
  } else if (t < 1376256) {
    src = wk; dst = wcat_bf + 1048576; t -= 1310720;
  } else if (t < 1441792) {
    src = wv; dst = wcat_bf + 1310720; t -= 1376256;
  } else {
    src = wo; dst = wo_bf; t -= 1441792;
  }
  const int i = t * 4;
  float4 v = *(const float4*)(src + i);
  uint2 p;
  p.x = (u32)f2bf(v.x) | ((u32)f2bf(v.y) << 16);
  p.y = (u32)f2bf(v.z) | ((u32)f2bf(v.w) << 16);
  *(uint2*)(dst + i) = p;
}

// ---------------- bf16 MFMA GEMM, single-wave workgroups ----------------
// C[M][N] = A[M][K] * B[N][K]^T. 64x64 tile per 64-thread block (1 wave):
// no inter-wave barriers (syncthreads = waitcnt only), 4x4 mfma_16x16x32 per
// BK=32 step, depth-1 register pipeline. Grid = (N/64, M/64) -> 1536/1024
// blocks = real oversubscription. A/B re-reads are L2/L3-resident.
template <typename OutT>
__global__ __launch_bounds__(64)
void gemm_bt_kernel(const u16* __restrict__ A, const u16* __restrict__ B,
                    OutT* __restrict__ C, int M, int N, int K) {
  __shared__ u16 As[64 * 32];  // 4 KB
  __shared__ u16 Bs[64 * 32];  // 4 KB
  const int lane = threadIdx.x;
  const int l15 = lane & 15;
  const int quad = lane >> 4;
  const int qk = quad * 8;
  const size_t bm = (size_t)blockIdx.y * 64;
  const size_t bn = (size_t)blockIdx.x * 64;

  f32x4 acc[4][4];
#pragma unroll
  for (int i = 0; i < 4; ++i)
#pragma unroll
    for (int j = 0; j < 4; ++j) acc[i][j] = f32x4{0.f, 0.f, 0.f, 0.f};

  const int srow = lane >> 2;       // 0..15
  const int scol = (lane & 3) * 8;  // 0,8,16,24
  const u16* Ab = A + (bm + srow) * (size_t)K + scol;
  const u16* Bb = B + (bn + srow) * (size_t)K + scol;

  uint4 ar[4], br[4];
#pragma unroll
  for (int s = 0; s < 4; ++s) {
    ar[s] = *(const uint4*)(Ab + (size_t)(s * 16) * K);
    br[s] = *(const uint4*)(Bb + (size_t)(s * 16) * K);
  }

  for (int k0 = 0; k0 < K; k0 += 32) {
    __syncthreads();  // single wave: waitcnt only, no inter-wave drain
#pragma unroll
    for (int s = 0; s < 4; ++s) {
      *(uint4*)(&As[(s * 16 + srow) * 32 + scol]) = ar[s];
      *(uint4*)(&Bs[(s * 16 + srow) * 32 + scol]) = br[s];
    }
    __syncthreads();
    const int kn = (k0 + 32 < K) ? k0 + 32 : 0;  // in-bounds dummy on last iter
#pragma unroll
    for (int s = 0; s < 4; ++s) {
      ar[s] = *(const uint4*)(Ab + (size_t)(s * 16) * K + kn);
      br[s] = *(const uint4*)(Bb + (size_t)(s * 16) * K + kn);
    }
    bf16x8 af[4], bfr[4];
#pragma unroll
    for (int i = 0; i < 4; ++i)
      af[i] = *(const bf16x8*)(&As[(i * 16 + l15) * 32 + qk]);
#pragma unroll
    for (int j = 0; j < 4; ++j)
      bfr[j] = *(const bf16x8*)(&Bs[(j * 16 + l15) * 32 + qk]);
#pragma unroll
    for (int i = 0; i < 4; ++i)
#pragma unroll
      for (int j = 0; j < 4; ++j)
        acc[i][j] = __builtin_amdgcn_mfma_f32_16x16x32_bf16(af[i], bfr[j], acc[i][j], 0, 0, 0);
  }

  const int rq = quad * 4;  // C/D row = quad*4 + reg
#pragma unroll
  for (int i = 0; i < 4; ++i) {
#pragma unroll
    for (int r = 0; r < 4; ++r) {
      OutT* crow = C + (bm + i * 16 + rq + r) * (size_t)N + bn + l15;
#pragma unroll
      for (int j = 0; j < 4; ++j) {
        if constexpr (sizeof(OutT) == 2)
          crow[j * 16] = f2bf(acc[i][j][r]);
        else
          crow[j * 16] = acc[i][j][r];
      }
    }
  }
}

// ---------------- fused: rmsnorm (blocks 0..4095) + V transpose (blocks 4096..4351) ----------------
__global__ __launch_bounds__(256)
void norm_vtrans_kernel(u16* __restrict__ qkv, const float* __restrict__ qw,
                        const float* __restrict__ kw, u16* __restrict__ vt) {
  __shared__ u16 shmem[64 * 72];
  const int bid = blockIdx.x;
  const int tid = threadIdx.x;
  if (bid < 4096) {
    float* red = (float*)shmem;
    u16* row = qkv + (size_t)bid * 1536;
    uint2 pk = *(const uint2*)(row + tid * 4);
    float v0 = bf2f((u16)pk.x), v1 = bf2f((u16)(pk.x >> 16));
    float v2 = bf2f((u16)pk.y), v3 = bf2f((u16)(pk.y >> 16));
    float ss = v0 * v0 + v1 * v1 + v2 * v2 + v3 * v3;
#pragma unroll
    for (int off = 32; off > 0; off >>= 1) ss += __shfl_down(ss, off);
    if ((tid & 63) == 0) red[tid >> 6] = ss;
    __syncthreads();
    float tot = red[0] + red[1] + red[2] + red[3];
    float rn = rsqrtf(tot * (1.0f / 1024.0f) + 1e-6f);
    float4 w = *(const float4*)(qw + tid * 4);
    uint2 po;
    po.x = (u32)f2bf(v0 * rn * w.x) | ((u32)f2bf(v1 * rn * w.y) << 16);
    po.y = (u32)f2bf(v2 * rn * w.z) | ((u32)f2bf(v3 * rn * w.w) << 16);
    *(uint2*)(row + tid * 4) = po;
    if (tid < 64) {
      uint2 kp = *(const uint2*)(row + 1024 + tid * 4);
      float k0 = bf2f((u16)kp.x), k1 = bf2f((u16)(kp.x >> 16));
      float k2 = bf2f((u16)kp.y), k3 = bf2f((u16)(kp.y >> 16));
      float sk = k0 * k0 + k1 * k1 + k2 * k2 + k3 * k3;
#pragma unroll
      for (int off = 32; off > 0; off >>= 1) sk += __shfl_down(sk, off);
      float tk = __shfl(sk, 0);
      float rk = rsqrtf(tk * (1.0f / 256.0f) + 1e-6f);
      float4 w2 = *(const float4*)(kw + tid * 4);
      uint2 ko;
      ko.x = (u32)f2bf(k0 * rk * w2.x) | ((u32)f2bf(k1 * rk * w2.y) << 16);
      ko.y = (u32)f2bf(k2 * rk * w2.z) | ((u32)f2bf(k3 * rk * w2.w) << 16);
      *(uint2*)(row + 1024 + tid * 4) = ko;
    }
  } else {
    const int e = bid - 4096;
    const int t0 = (e & 31) * 64, kvh = (e >> 5) & 3, b = e >> 7;
    u16(*tile)[72] = (u16(*)[72])shmem;
    const int r = tid >> 2, c16 = (tid & 3) * 16;
    const u16* src = qkv + (size_t)(b * 2048 + t0 + r) * 1536 + 1280 + kvh * 64 + c16;
    *(uint4*)&tile[r][c16] = *(const uint4*)src;
    *(uint4*)&tile[r][c16 + 8] = *(const uint4*)(src + 8);
    __syncthreads();
    const int d = tid >> 2, t16 = (tid & 3) * 16;
    u16 o[16];
#pragma unroll
    for (int j = 0; j < 16; ++j) o[j] = tile[t16 + j][d];
    u16* dst = vt + (size_t)((b * 4 + kvh) * 64 + d) * 2048 + t0 + t16;
    *(uint4*)dst = *(uint4*)&o[0];
    *(uint4*)(dst + 8) = *(uint4*)&o[8];
  }
}

// ---------------- MFMA flash attention: 128-q blocks, 8 waves ----------------
__global__ __launch_bounds__(512)
void attn_kernel(const u16* __restrict__ qkvbf, const u16* __restrict__ vt,
                 u16* __restrict__ ybf) {
  __shared__ u16 Ks[64 * 72];
  __shared__ u16 Vts[64 * 72];
  __shared__ u16 Ps[128 * 72];
  const int qt = blockIdx.x, h = blockIdx.y, b = blockIdx.z;
  const int kvh = h >> 2, q0 = qt * 128;
  const int tid = threadIdx.x, lane = tid & 63, w = tid >> 6;  // w 0..7
  const int l15 = lane & 15, quad = lane >> 4;

  const u16* qrow = qkvbf + (size_t)(b * 2048 + q0 + w * 16 + l15) * 1536 + h * 64 + quad * 8;
  const bf16x8 qf0 = *(const bf16x8*)qrow;
  const bf16x8 qf1 = *(const bf16x8*)(qrow + 32);

  const int sr = tid >> 3, sc = (tid & 7) * 8;
  const u16* kbase = qkvbf + (size_t)(b * 2048 + sr) * 1536 + 1024 + kvh * 64 + sc;
  const u16* vbase = vt + (size_t)((b * 4 + kvh) * 64 + sr) * 2048 + sc;

  f32x4 O[4];
#pragma unroll
  for (int jd = 0; jd < 4; ++jd) O[jd] = f32x4{0.f, 0.f, 0.f, 0.f};
  float m_i = -1e30f, l_i = 0.f;
  const float LOG2E = 1.44269504f;
  const float sc2 = 0.125f * LOG2E;
  const float slope2 = exp2f(-0.5f * (float)(h + 1)) * LOG2E;
  const int c_lo = (q0 >= 512) ? (q0 - 512) : 0;
  const int c_hi = q0 + 64;
  const int myq_lo = q0 + w * 16;
  const int myq_hi = myq_lo + 15;
  const int myq = myq_lo + l15;

  uint4 kr = *(const uint4*)(kbase + (size_t)c_lo * 1536);
  uint4 vr = *(const uint4*)(vbase + c_lo);

  for (int c = c_lo; c <= c_hi; c += 64) {
    __syncthreads();
    *(uint4*)&Ks[sr * 72 + sc] = kr;
    *(uint4*)&Vts[sr * 72 + sc] = vr;
    __syncthreads();
    {
      const int cn = (c + 64 <= c_hi) ? c + 64 : c_lo;
      kr = *(const uint4*)(kbase + (size_t)cn * 1536);
      vr = *(const uint4*)(vbase + cn);
    }

    if (c > myq_hi || c + 63 < myq_lo - 512) continue;

    f32x4 st[4];
#pragma unroll
    for (int i = 0; i < 4; ++i) {
      bf16x8 a0 = *(const bf16x8*)&Ks[(i * 16 + l15) * 72 + quad * 8];
      bf16x8 a1 = *(const bf16x8*)&Ks[(i * 16 + l15) * 72 + 32 + quad * 8];
      f32x4 z = f32x4{0.f, 0.f, 0.f, 0.f};
      z = __builtin_amdgcn_mfma_f32_16x16x32_bf16(a0, qf0, z, 0, 0, 0);
      st[i] = __builtin_amdgcn_mfma_f32_16x16x32_bf16(a1, qf1, z, 0, 0, 0);
    }

    float sv[4][4];
    float rm = -1e30f;
    const bool interior = (c + 63 <= myq_lo) && (c + 512 >= myq_hi);
    if (interior) {
#pragma unroll
      for (int i = 0; i < 4; ++i)
#pragma unroll
        for (int r = 0; r < 4; ++r) {
          const int key = c + i * 16 + quad * 4 + r;
          float val = st[i][r] * sc2 + slope2 * (float)(key - myq);
          sv[i][r] = val;
          rm = fmaxf(rm, val);
        }
    } else {
#pragma unroll
      for (int i = 0; i < 4; ++i)
#pragma unroll
        for (int r = 0; r < 4; ++r) {
          const int key = c + i * 16 + quad * 4 + r;
          const int rel = key - myq;
          float val = (rel > 0 || rel < -512) ? -1e30f
                                              : st[i][r] * sc2 + slope2 * (float)rel;
          sv[i][r] = val;
          rm = fmaxf(rm, val);
        }
    }
    rm = fmaxf(rm, __shfl_xor(rm, 16));
    rm = fmaxf(rm, __shfl_xor(rm, 32));
    const float mn = fmaxf(m_i, rm);
    const float alpha = exp2f(m_i - mn);
    float ls = 0.f;
#pragma unroll
    for (int i = 0; i < 4; ++i) {
      float p0 = exp2f(sv[i][0] - mn);
      float p1 = exp2f(sv[i][1] - mn);
      float p2 = exp2f(sv[i][2] - mn);
      float p3 = exp2f(sv[i][3] - mn);
      ls += (p0 + p1) + (p2 + p3);
      uint2 pw;
      pw.x = (u32)f2bf(p0) | ((u32)f2bf(p1) << 16);
      pw.y = (u32)f2bf(p2) | ((u32)f2bf(p3) << 16);
      *(uint2*)&Ps[(w * 16 + l15) * 72 + i * 16 + quad * 4] = pw;
    }
    ls += __shfl_xor(ls, 16);
    ls += __shfl_xor(ls, 32);
    l_i = l_i * alpha + ls;
    m_i = mn;

    float ar[4];
#pragma unroll
    for (int r = 0; r < 4; ++r) ar[r] = __shfl(alpha, quad * 4 + r);
#pragma unroll
    for (int jd = 0; jd < 4; ++jd)
#pragma unroll
      for (int r = 0; r < 4; ++r) O[jd][r] *= ar[r];

    bf16x8 pf0 = *(const bf16x8*)&Ps[(w * 16 + l15) * 72 + quad * 8];
    bf16x8 pf1 = *(const bf16x8*)&Ps[(w * 16 + l15) * 72 + 32 + quad * 8];
#pragma unroll
    for (int jd = 0; jd < 4; ++jd) {
      bf16x8 v0 = *(const bf16x8*)&Vts[(jd * 16 + l15) * 72 + quad * 8];
      bf16x8 v1 = *(const bf16x8*)&Vts[(jd * 16 + l15) * 72 + 32 + quad * 8];
      O[jd] = __builtin_amdgcn_mfma_f32_16x16x32_bf16(pf0, v0, O[jd], 0, 0, 0);
      O[jd] = __builtin_amdgcn_mfma_f32_16x16x32_bf16(pf1, v1, O[jd], 0, 0, 0);
    }
  }

  float lr[4];
#pragma unroll
  for (int r = 0; r < 4; ++r) lr[r] = __shfl(l_i, quad * 4 + r);
#pragma unroll
  for (int r = 0; r < 4; ++r) {
    const float inv = 1.0f / lr[r];
    u16* orow = ybf + (size_t)(b * 2048 + q0 + w * 16 + quad * 4 + r) * 1024 + h * 64 + l15;
#pragma unroll
    for (int jd = 0; jd < 4; ++jd) orow[jd * 16] = f2bf(O[jd][r] * inv);
  }
}

// ---------------- launch ----------------
extern "C" void kernel_launch(void* const* d_in, const int* in_sizes, int n_in,
                              void* d_out, int out_size, void* d_ws, size_t ws_size,
                              hipStream_t stream) {
  const float* x = (const float*)d_in[0];
  const float* wq = (const float*)d_in[1];
  const float* wk = (const float*)d_in[2];
  const float* wv = (const float*)d_in[3];
  const float* wo = (const float*)d_in[4];
  const float* qnw = (const float*)d_in[5];
  const float* knw = (const float*)d_in[6];
  float* out = (float*)d_out;
  char* ws = (char*)d_ws;

  u16* x_bf = (u16*)(ws);                     // 4096x1024
  u16* wcat_bf = (u16*)(ws + 8388608);        // 1536x1024
  u16* wo_bf = (u16*)(ws + 11534336);         // 1024x1024
  u16* qkv_bf = (u16*)(ws + 13631488);        // 4096x1536
  u16* vt_bf = (u16*)(ws + 26214400);         // 2x4x64x2048
  u16* y_bf = (u16*)(ws + 28311552);          // 4096x1024

  cvt_all_kernel<<<6656, 256, 0, stream>>>(x, wq, wk, wv, wo, x_bf, wcat_bf, wo_bf);

  gemm_bt_kernel<u16><<<dim3(24, 64), 64, 0, stream>>>(x_bf, wcat_bf, qkv_bf, 4096, 1536, 1024);
  norm_vtrans_kernel<<<4352, 256, 0, stream>>>(qkv_bf, qnw, knw, vt_bf);
  attn_kernel<<<dim3(16, 16, 2), 512, 0, stream>>>(qkv_bf, vt_bf, y_bf);
  gemm_bt_kernel<float><<<dim3(16, 64), 64, 0, stream>>>(y_bf, wo_bf, out, 4096, 1024, 1024);
}

// Round 8
// 160.292 us; speedup vs baseline: 1.9402x; 1.9402x over previous
//
#include <hip/hip_runtime.h>

typedef unsigned short u16;
typedef unsigned int u32;

typedef __bf16 bf16x8 __attribute__((ext_vector_type(8)));
typedef float f32x4 __attribute__((ext_vector_type(4)));

__device__ __forceinline__ u16 f2bf(float f) {
  u32 u = __builtin_bit_cast(u32, f);
  u32 r = (u + 0x7fffu + ((u >> 16) & 1u)) >> 16;  // RNE
  return (u16)r;
}
__device__ __forceinline__ float bf2f(u16 v) {
  u32 u = (u32)v << 16;
  return __builtin_bit_cast(float, u);
}

// ---------------- fused f32 -> bf16 convert for all 5 tensors ----------------
__global__ __launch_bounds__(256)
void cvt_all_kernel(const float* __restrict__ x, const float* __restrict__ wq,
                    const float* __restrict__ wk, const float* __restrict__ wv,
                    const float* __restrict__ wo, u16* __restrict__ x_bf,
                    u16* __restrict__ wcat_bf, u16* __restrict__ wo_bf) {
  int t = blockIdx.x * 256 + threadIdx.x;
  const float* src;
  u16* dst;
  if (t < 1048576) {
    src = x; dst = x_bf;
  } else if (t < 1310720) {
    src = wq; dst = wcat_bf; t -= 1048576;
  } else if (t < 1376256) {
    src = wk; dst = wcat_bf + 1048576; t -= 1310720;
  } else if (t < 1441792) {
    src = wv; dst = wcat_bf + 1310720; t -= 1376256;
  } else {
    src = wo; dst = wo_bf; t -= 1441792;
  }
  const int i = t * 4;
  float4 v = *(const float4*)(src + i);
  uint2 p;
  p.x = (u32)f2bf(v.x) | ((u32)f2bf(v.y) << 16);
  p.y = (u32)f2bf(v.z) | ((u32)f2bf(v.w) << 16);
  *(uint2*)(dst + i) = p;
}

// ---------------- bf16 MFMA GEMM: C[M][N] = A[M][K] * B[N][K]^T ----------------
// 64x128 tile, BK=64 (half the barriers of BK=32), 4 waves 2x2 (wave tile 32x64),
// depth-1 register prefetch. LDS is XOR-swizzled in 16B blocks (block ^= row&7):
// conflict-free staging writes AND fragment reads with the unpadded 128B row
// stride; global reads stay coalesced (swizzle is LDS-destination-only).
template <typename OutT>
__global__ __launch_bounds__(256)
void gemm_bt_kernel(const u16* __restrict__ A, const u16* __restrict__ B,
                    OutT* __restrict__ C, int M, int N, int K) {
  __shared__ u16 As[64 * 64];    // 8 KB
  __shared__ u16 Bs[128 * 64];   // 16 KB
  const int tid = threadIdx.x;
  const int lane = tid & 63;
  const int wave = tid >> 6;
  const int wm = (wave >> 1) * 32;   // 0 / 32
  const int wn = (wave & 1) * 64;    // 0 / 64
  const int l15 = lane & 15;
  const int quad = lane >> 4;
  const int sw = l15 & 7;            // per-lane fragment swizzle key (row&7)
  const size_t bm = (size_t)blockIdx.y * 64;
  const size_t bn = (size_t)blockIdx.x * 128;

  f32x4 acc[2][4];
#pragma unroll
  for (int i = 0; i < 2; ++i)
#pragma unroll
    for (int j = 0; j < 4; ++j) acc[i][j] = f32x4{0.f, 0.f, 0.f, 0.f};

  // staging: uint4 index u (0..511 for A, 0..1023 for B): row=u>>3, blk=u&7
  // A: u in {tid, tid+256}; B: u in {tid, tid+256, tid+512, tid+768}
  const int ra0 = tid >> 3, ba0 = tid & 7;               // A part 0
  const int ra1 = (tid + 256) >> 3, ba1 = tid & 7;       // A part 1
  const u16* Ap0 = A + (bm + ra0) * (size_t)K + ba0 * 8;
  const u16* Ap1 = A + (bm + ra1) * (size_t)K + ba1 * 8;
  const u16* Bp0 = B + (bn + ra0) * (size_t)K + ba0 * 8;
  const u16* Bp1 = B + (bn + ra1) * (size_t)K + ba1 * 8;
  const u16* Bp2 = B + (bn + ra0 + 64) * (size_t)K + ba0 * 8;
  const u16* Bp3 = B + (bn + ra1 + 64) * (size_t)K + ba1 * 8;
  // swizzled LDS write offsets (u16 units)
  const int wa0 = ra0 * 64 + ((ba0 ^ (ra0 & 7)) * 8);
  const int wa1 = ra1 * 64 + ((ba1 ^ (ra1 & 7)) * 8);
  const int wb2 = (ra0 + 64) * 64 + ((ba0 ^ (ra0 & 7)) * 8);
  const int wb3 = (ra1 + 64) * 64 + ((ba1 ^ (ra1 & 7)) * 8);

  uint4 a0 = *(const uint4*)Ap0, a1 = *(const uint4*)Ap1;
  uint4 b0 = *(const uint4*)Bp0, b1 = *(const uint4*)Bp1;
  uint4 b2 = *(const uint4*)Bp2, b3 = *(const uint4*)Bp3;

  for (int k0 = 0; k0 < K; k0 += 64) {
    __syncthreads();
    *(uint4*)(&As[wa0]) = a0;
    *(uint4*)(&As[wa1]) = a1;
    *(uint4*)(&Bs[wa0]) = b0;
    *(uint4*)(&Bs[wa1]) = b1;
    *(uint4*)(&Bs[wb2]) = b2;
    *(uint4*)(&Bs[wb3]) = b3;
    __syncthreads();
    const int kn = (k0 + 64 < K) ? k0 + 64 : 0;  // in-bounds dummy on last iter
    a0 = *(const uint4*)(Ap0 + kn);
    a1 = *(const uint4*)(Ap1 + kn);
    b0 = *(const uint4*)(Bp0 + kn);
    b1 = *(const uint4*)(Bp1 + kn);
    b2 = *(const uint4*)(Bp2 + kn);
    b3 = *(const uint4*)(Bp3 + kn);
#pragma unroll
    for (int h = 0; h < 2; ++h) {
      const int cb = (quad + 4 * h);  // k block 0..7
      bf16x8 af[2], bfr[4];
#pragma unroll
      for (int i = 0; i < 2; ++i)
        af[i] = *(const bf16x8*)(&As[(wm + i * 16 + l15) * 64 + ((cb ^ sw) * 8)]);
#pragma unroll
      for (int j = 0; j < 4; ++j)
        bfr[j] = *(const bf16x8*)(&Bs[(wn + j * 16 + l15) * 64 + ((cb ^ sw) * 8)]);
#pragma unroll
      for (int i = 0; i < 2; ++i)
#pragma unroll
        for (int j = 0; j < 4; ++j)
          acc[i][j] = __builtin_amdgcn_mfma_f32_16x16x32_bf16(af[i], bfr[j], acc[i][j], 0, 0, 0);
    }
  }

  const int rq = quad * 4;
#pragma unroll
  for (int i = 0; i < 2; ++i) {
#pragma unroll
    for (int r = 0; r < 4; ++r) {
      OutT* crow = C + (bm + wm + i * 16 + rq + r) * (size_t)N + bn + wn + l15;
#pragma unroll
      for (int j = 0; j < 4; ++j) {
        if constexpr (sizeof(OutT) == 2)
          crow[j * 16] = f2bf(acc[i][j][r]);
        else
          crow[j * 16] = acc[i][j][r];
      }
    }
  }
}

// ---------------- fused: rmsnorm (blocks 0..4095) + V transpose (blocks 4096..4351) ----------------
__global__ __launch_bounds__(256)
void norm_vtrans_kernel(u16* __restrict__ qkv, const float* __restrict__ qw,
                        const float* __restrict__ kw, u16* __restrict__ vt) {
  __shared__ u16 shmem[64 * 72];
  const int bid = blockIdx.x;
  const int tid = threadIdx.x;
  if (bid < 4096) {
    float* red = (float*)shmem;
    u16* row = qkv + (size_t)bid * 1536;
    uint2 pk = *(const uint2*)(row + tid * 4);
    float v0 = bf2f((u16)pk.x), v1 = bf2f((u16)(pk.x >> 16));
    float v2 = bf2f((u16)pk.y), v3 = bf2f((u16)(pk.y >> 16));
    float ss = v0 * v0 + v1 * v1 + v2 * v2 + v3 * v3;
#pragma unroll
    for (int off = 32; off > 0; off >>= 1) ss += __shfl_down(ss, off);
    if ((tid & 63) == 0) red[tid >> 6] = ss;
    __syncthreads();
    float tot = red[0] + red[1] + red[2] + red[3];
    float rn = rsqrtf(tot * (1.0f / 1024.0f) + 1e-6f);
    float4 w = *(const float4*)(qw + tid * 4);
    uint2 po;
    po.x = (u32)f2bf(v0 * rn * w.x) | ((u32)f2bf(v1 * rn * w.y) << 16);
    po.y = (u32)f2bf(v2 * rn * w.z) | ((u32)f2bf(v3 * rn * w.w) << 16);
    *(uint2*)(row + tid * 4) = po;
    if (tid < 64) {
      uint2 kp = *(const uint2*)(row + 1024 + tid * 4);
      float k0 = bf2f((u16)kp.x), k1 = bf2f((u16)(kp.x >> 16));
      float k2 = bf2f((u16)kp.y), k3 = bf2f((u16)(kp.y >> 16));
      float sk = k0 * k0 + k1 * k1 + k2 * k2 + k3 * k3;
#pragma unroll
      for (int off = 32; off > 0; off >>= 1) sk += __shfl_down(sk, off);
      float tk = __shfl(sk, 0);
      float rk = rsqrtf(tk * (1.0f / 256.0f) + 1e-6f);
      float4 w2 = *(const float4*)(kw + tid * 4);
      uint2 ko;
      ko.x = (u32)f2bf(k0 * rk * w2.x) | ((u32)f2bf(k1 * rk * w2.y) << 16);
      ko.y = (u32)f2bf(k2 * rk * w2.z) | ((u32)f2bf(k3 * rk * w2.w) << 16);
      *(uint2*)(row + 1024 + tid * 4) = ko;
    }
  } else {
    const int e = bid - 4096;
    const int t0 = (e & 31) * 64, kvh = (e >> 5) & 3, b = e >> 7;
    u16(*tile)[72] = (u16(*)[72])shmem;
    const int r = tid >> 2, c16 = (tid & 3) * 16;
    const u16* src = qkv + (size_t)(b * 2048 + t0 + r) * 1536 + 1280 + kvh * 64 + c16;
    *(uint4*)&tile[r][c16] = *(const uint4*)src;
    *(uint4*)&tile[r][c16 + 8] = *(const uint4*)(src + 8);
    __syncthreads();
    const int d = tid >> 2, t16 = (tid & 3) * 16;
    u16 o[16];
#pragma unroll
    for (int j = 0; j < 16; ++j) o[j] = tile[t16 + j][d];
    u16* dst = vt + (size_t)((b * 4 + kvh) * 64 + d) * 2048 + t0 + t16;
    *(uint4*)dst = *(uint4*)&o[0];
    *(uint4*)(dst + 8) = *(uint4*)&o[8];
  }
}

// ---------------- MFMA flash attention: 128-q blocks, 8 waves ----------------
__global__ __launch_bounds__(512)
void attn_kernel(const u16* __restrict__ qkvbf, const u16* __restrict__ vt,
                 u16* __restrict__ ybf) {
  __shared__ u16 Ks[64 * 72];
  __shared__ u16 Vts[64 * 72];
  __shared__ u16 Ps[128 * 72];
  const int qt = blockIdx.x, h = blockIdx.y, b = blockIdx.z;
  const int kvh = h >> 2, q0 = qt * 128;
  const int tid = threadIdx.x, lane = tid & 63, w = tid >> 6;  // w 0..7
  const int l15 = lane & 15, quad = lane >> 4;

  const u16* qrow = qkvbf + (size_t)(b * 2048 + q0 + w * 16 + l15) * 1536 + h * 64 + quad * 8;
  const bf16x8 qf0 = *(const bf16x8*)qrow;
  const bf16x8 qf1 = *(const bf16x8*)(qrow + 32);

  const int sr = tid >> 3, sc = (tid & 7) * 8;
  const u16* kbase = qkvbf + (size_t)(b * 2048 + sr) * 1536 + 1024 + kvh * 64 + sc;
  const u16* vbase = vt + (size_t)((b * 4 + kvh) * 64 + sr) * 2048 + sc;

  f32x4 O[4];
#pragma unroll
  for (int jd = 0; jd < 4; ++jd) O[jd] = f32x4{0.f, 0.f, 0.f, 0.f};
  float m_i = -1e30f, l_i = 0.f;
  const float LOG2E = 1.44269504f;
  const float sc2 = 0.125f * LOG2E;
  const float slope2 = exp2f(-0.5f * (float)(h + 1)) * LOG2E;
  const int c_lo = (q0 >= 512) ? (q0 - 512) : 0;
  const int c_hi = q0 + 64;
  const int myq_lo = q0 + w * 16;
  const int myq_hi = myq_lo + 15;
  const int myq = myq_lo + l15;

  uint4 kr = *(const uint4*)(kbase + (size_t)c_lo * 1536);
  uint4 vr = *(const uint4*)(vbase + c_lo);

  for (int c = c_lo; c <= c_hi; c += 64) {
    __syncthreads();
    *(uint4*)&Ks[sr * 72 + sc] = kr;
    *(uint4*)&Vts[sr * 72 + sc] = vr;
    __syncthreads();
    {
      const int cn = (c + 64 <= c_hi) ? c + 64 : c_lo;
      kr = *(const uint4*)(kbase + (size_t)cn * 1536);
      vr = *(const uint4*)(vbase + cn);
    }

    if (c > myq_hi || c + 63 < myq_lo - 512) continue;

    f32x4 st[4];
#pragma unroll
    for (int i = 0; i < 4; ++i) {
      bf16x8 a0 = *(const bf16x8*)&Ks[(i * 16 + l15) * 72 + quad * 8];
      bf16x8 a1 = *(const bf16x8*)&Ks[(i * 16 + l15) * 72 + 32 + quad * 8];
      f32x4 z = f32x4{0.f, 0.f, 0.f, 0.f};
      z = __builtin_amdgcn_mfma_f32_16x16x32_bf16(a0, qf0, z, 0, 0, 0);
      st[i] = __builtin_amdgcn_mfma_f32_16x16x32_bf16(a1, qf1, z, 0, 0, 0);
    }

    float sv[4][4];
    float rm = -1e30f;
    const bool interior = (c + 63 <= myq_lo) && (c + 512 >= myq_hi);
    if (interior) {
#pragma unroll
      for (int i = 0; i < 4; ++i)
#pragma unroll
        for (int r = 0; r < 4; ++r) {
          const int key = c + i * 16 + quad * 4 + r;
          float val = st[i][r] * sc2 + slope2 * (float)(key - myq);
          sv[i][r] = val;
          rm = fmaxf(rm, val);
        }
    } else {
#pragma unroll
      for (int i = 0; i < 4; ++i)
#pragma unroll
        for (int r = 0; r < 4; ++r) {
          const int key = c + i * 16 + quad * 4 + r;
          const int rel = key - myq;
          float val = (rel > 0 || rel < -512) ? -1e30f
                                              : st[i][r] * sc2 + slope2 * (float)rel;
          sv[i][r] = val;
          rm = fmaxf(rm, val);
        }
    }
    rm = fmaxf(rm, __shfl_xor(rm, 16));
    rm = fmaxf(rm, __shfl_xor(rm, 32));
    const float mn = fmaxf(m_i, rm);
    const float alpha = exp2f(m_i - mn);
    float ls = 0.f;
#pragma unroll
    for (int i = 0; i < 4; ++i) {
      float p0 = exp2f(sv[i][0] - mn);
      float p1 = exp2f(sv[i][1] - mn);
      float p2 = exp2f(sv[i][2] - mn);
      float p3 = exp2f(sv[i][3] - mn);
      ls += (p0 + p1) + (p2 + p3);
      uint2 pw;
      pw.x = (u32)f2bf(p0) | ((u32)f2bf(p1) << 16);
      pw.y = (u32)f2bf(p2) | ((u32)f2bf(p3) << 16);
      *(uint2*)&Ps[(w * 16 + l15) * 72 + i * 16 + quad * 4] = pw;
    }
    ls += __shfl_xor(ls, 16);
    ls += __shfl_xor(ls, 32);
    l_i = l_i * alpha + ls;
    m_i = mn;

    float ar[4];
#pragma unroll
    for (int r = 0; r < 4; ++r) ar[r] = __shfl(alpha, quad * 4 + r);
#pragma unroll
    for (int jd = 0; jd < 4; ++jd)
#pragma unroll
      for (int r = 0; r < 4; ++r) O[jd][r] *= ar[r];

    bf16x8 pf0 = *(const bf16x8*)&Ps[(w * 16 + l15) * 72 + quad * 8];
    bf16x8 pf1 = *(const bf16x8*)&Ps[(w * 16 + l15) * 72 + 32 + quad * 8];
#pragma unroll
    for (int jd = 0; jd < 4; ++jd) {
      bf16x8 v0 = *(const bf16x8*)&Vts[(jd * 16 + l15) * 72 + quad * 8];
      bf16x8 v1 = *(const bf16x8*)&Vts[(jd * 16 + l15) * 72 + 32 + quad * 8];
      O[jd] = __builtin_amdgcn_mfma_f32_16x16x32_bf16(pf0, v0, O[jd], 0, 0, 0);
      O[jd] = __builtin_amdgcn_mfma_f32_16x16x32_bf16(pf1, v1, O[jd], 0, 0, 0);
    }
  }

  float lr[4];
#pragma unroll
  for (int r = 0; r < 4; ++r) lr[r] = __shfl(l_i, quad * 4 + r);
#pragma unroll
  for (int r = 0; r < 4; ++r) {
    const float inv = 1.0f / lr[r];
    u16* orow = ybf + (size_t)(b * 2048 + q0 + w * 16 + quad * 4 + r) * 1024 + h * 64 + l15;
#pragma unroll
    for (int jd = 0; jd < 4; ++jd) orow[jd * 16] = f2bf(O[jd][r] * inv);
  }
}

// ---------------- launch ----------------
extern "C" void kernel_launch(void* const* d_in, const int* in_sizes, int n_in,
                              void* d_out, int out_size, void* d_ws, size_t ws_size,
                              hipStream_t stream) {
  const float* x = (const float*)d_in[0];
  const float* wq = (const float*)d_in[1];
  const float* wk = (const float*)d_in[2];
  const float* wv = (const float*)d_in[3];
  const float* wo = (const float*)d_in[4];
  const float* qnw = (const float*)d_in[5];
  const float* knw = (const float*)d_in[6];
  float* out = (float*)d_out;
  char* ws = (char*)d_ws;

  u16* x_bf = (u16*)(ws);                     // 4096x1024
  u16* wcat_bf = (u16*)(ws + 8388608);        // 1536x1024
  u16* wo_bf = (u16*)(ws + 11534336);         // 1024x1024
  u16* qkv_bf = (u16*)(ws + 13631488);        // 4096x1536
  u16* vt_bf = (u16*)(ws + 26214400);         // 2x4x64x2048
  u16* y_bf = (u16*)(ws + 28311552);          // 4096x1024

  cvt_all_kernel<<<6656, 256, 0, stream>>>(x, wq, wk, wv, wo, x_bf, wcat_bf, wo_bf);

  gemm_bt_kernel<u16><<<dim3(12, 64), 256, 0, stream>>>(x_bf, wcat_bf, qkv_bf, 4096, 1536, 1024);
  norm_vtrans_kernel<<<4352, 256, 0, stream>>>(qkv_bf, qnw, knw, vt_bf);
  attn_kernel<<<dim3(16, 16, 2), 512, 0, stream>>>(qkv_bf, vt_bf, y_bf);
  gemm_bt_kernel<float><<<dim3(8, 64), 256, 0, stream>>>(y_bf, wo_bf, out, 4096, 1024, 1024);
}